// Round 1
// baseline (151.312 us; speedup 1.0000x reference)
//
#include <hip/hip_runtime.h>
#include <math.h>

#define B_  64
#define N_  512
#define E_  8
#define D_  64
#define TI  4    // i-rows per block in fused kernel

typedef float f32x4 __attribute__((ext_vector_type(4)));

// ---------------- Kernel 1: pre_sup = x @ W  ([32768,64] @ [64,64]) ----------
__global__ __launch_bounds__(256) void presup_kernel(
    const float* __restrict__ x, const float* __restrict__ W, float* __restrict__ ps)
{
    __shared__ float Wl[64 * 64];
    const int t = threadIdx.x;
#pragma unroll
    for (int i = 0; i < 4; ++i)
        ((f32x4*)Wl)[t + i * 256] = ((const f32x4*)W)[t + i * 256];
    __syncthreads();

    const int d4  = (t & 15) * 4;   // 16 lanes cover d=0..63 as float4
    const int r   = t >> 4;         // 16 rows per block
    const int row = blockIdx.x * 16 + r;
    const float* xr = x + (size_t)row * 64;

    f32x4 acc = 0.f;
#pragma unroll
    for (int k = 0; k < 64; k += 4) {
        f32x4 xv = *(const f32x4*)&xr[k];
        f32x4 w0 = *(const f32x4*)&Wl[(k + 0) * 64 + d4];
        f32x4 w1 = *(const f32x4*)&Wl[(k + 1) * 64 + d4];
        f32x4 w2 = *(const f32x4*)&Wl[(k + 2) * 64 + d4];
        f32x4 w3 = *(const f32x4*)&Wl[(k + 3) * 64 + d4];
        acc += xv.x * w0;
        acc += xv.y * w1;
        acc += xv.z * w2;
        acc += xv.w * w3;
    }
    *(f32x4*)&ps[(size_t)row * 64 + d4] = acc;
}

// ------- Kernel 2: fused scores -> softmax -> 0.5*(A+I)-weighted agg --------
// One block handles TI=4 consecutive i-rows of one batch b.
__global__ __launch_bounds__(256) void fused_kernel(
    const float* __restrict__ edge, const float* __restrict__ coef,
    const float* __restrict__ ps, float* __restrict__ out)
{
    __shared__ alignas(16) float s4[N_][TI];        // s4[j][r]: unnormalized p (8 KB)
    __shared__ float denom[TI];
    __shared__ alignas(16) float part[16][TI * 64]; // jg partials (16 KB)

    const int t  = threadIdx.x;
    const int b  = blockIdx.x >> 7;          // / (N/TI)=128
    const int i0 = (blockIdx.x & 127) * TI;

    const float c0 = coef[0], c1 = coef[1], c2 = coef[2], c3 = coef[3];
    const float c4 = coef[4], c5 = coef[5], c6 = coef[6], c7 = coef[7];

    // ---- Phase A: per-edge scores (the single HBM pass over edge_features) ----
    {
        const size_t rowbase = ((size_t)b * N_ + i0) * (size_t)(N_ * E_);
#pragma unroll
        for (int r = 0; r < TI; ++r) {
#pragma unroll
            for (int jj = 0; jj < 2; ++jj) {
                const int j = t + jj * 256;
                const f32x4* ep = (const f32x4*)(edge + rowbase
                                    + (size_t)r * (N_ * E_) + (size_t)j * E_);
                f32x4 e0 = __builtin_nontemporal_load(ep);
                f32x4 e1 = __builtin_nontemporal_load(ep + 1);
                // TAU == 1.0, fold /TAU away
                s4[j][r] = e0.x * c0 + e0.y * c1 + e0.z * c2 + e0.w * c3
                         + e1.x * c4 + e1.y * c5 + e1.z * c6 + e1.w * c7;
            }
        }
    }
    __syncthreads();

    // ---- Phase B: softmax per row (wave w owns row w), keep p UNNORMALIZED ----
    {
        const int w = t >> 6, l = t & 63;
        float m = -INFINITY;
#pragma unroll
        for (int k = 0; k < N_ / 64; ++k) m = fmaxf(m, s4[l + k * 64][w]);
#pragma unroll
        for (int off = 32; off; off >>= 1) m = fmaxf(m, __shfl_xor(m, off, 64));
        float sum = 0.f;
#pragma unroll
        for (int k = 0; k < N_ / 64; ++k) {
            float p = __expf(s4[l + k * 64][w] - m);
            s4[l + k * 64][w] = p;
            sum += p;
        }
#pragma unroll
        for (int off = 32; off; off >>= 1) sum += __shfl_xor(sum, off, 64);
        if (l == 0) denom[w] = sum;
    }
    __syncthreads();

    // ---- Phase C: acc[r][d] = sum_j p[r][j] * pre_sup[b,j,d] ----
    // thread t: d-quad d4=(t&15)*4, j-group jg=t>>4; j = jg + 16k so a wave's
    // 4 subgroups read consecutive j (contiguous 1 KiB global, conflict-free
    // b128 broadcast of s4[j][0..3]).
    const int d4 = (t & 15) * 4;
    const int jg = t >> 4;
    const float* psb = ps + (size_t)b * (N_ * D_);

    f32x4 a0 = 0.f, a1 = 0.f, a2 = 0.f, a3 = 0.f;
#pragma unroll 4
    for (int k = 0; k < N_ / 16; ++k) {
        const int j = jg + (k << 4);
        f32x4 v  = *(const f32x4*)&psb[j * D_ + d4];
        f32x4 pv = *(const f32x4*)&s4[j][0];
        a0 += pv.x * v;
        a1 += pv.y * v;
        a2 += pv.z * v;
        a3 += pv.w * v;
    }
    *(f32x4*)&part[jg][0 * 64 + d4] = a0;
    *(f32x4*)&part[jg][1 * 64 + d4] = a1;
    *(f32x4*)&part[jg][2 * 64 + d4] = a2;
    *(f32x4*)&part[jg][3 * 64 + d4] = a3;
    __syncthreads();

    // ---- Final: reduce 16 partials, fold 1/denom, +self, *0.5, relu ----
    {
        const int r2 = t >> 6, d = t & 63;
        float sum = 0.f;
#pragma unroll
        for (int g = 0; g < 16; ++g) sum += part[g][t];
        const int row = i0 + r2;
        const float val = 0.5f * (sum / denom[r2] + psb[row * D_ + d]);
        out[((size_t)b * N_ + row) * D_ + d] = fmaxf(val, 0.f);
    }
}

extern "C" void kernel_launch(void* const* d_in, const int* in_sizes, int n_in,
                              void* d_out, int out_size, void* d_ws, size_t ws_size,
                              hipStream_t stream) {
    const float* edge = (const float*)d_in[0];  // [64,512,512,8]
    const float* x    = (const float*)d_in[1];  // [32768,64]
    const float* W    = (const float*)d_in[2];  // [64,64]
    const float* coef = (const float*)d_in[3];  // [8,1]
    float* out = (float*)d_out;                 // [32768,64]
    float* ps  = (float*)d_ws;                  // pre_sup scratch: 8 MiB

    presup_kernel<<<(B_ * N_) / 16, 256, 0, stream>>>(x, W, ps);
    fused_kernel<<<B_ * (N_ / TI), 256, 0, stream>>>(edge, coef, ps, out);
}